// Round 10
// baseline (269.465 us; speedup 1.0000x reference)
//
#include <hip/hip_runtime.h>
#include <hip/hip_bf16.h>
#include <math.h>

#define NV 8192
#define NE 2048
#define CIN 128
#define COUT 128
#define NH 4
#define HID 32
#define ETILE 8
#define LCAP 256
#define VCAP 96
#define NWORDS (NE / 64)
#define TWORDS (NV / 64)
#define EPSV 1e-5f

__device__ __forceinline__ float gelu_f(float x) {
    return 0.5f * x * (1.0f + erff(x * 0.70710678118654752f));
}
__device__ __forceinline__ float sigmoid_f(float x) {
    return 1.0f / (1.0f + expf(-x));
}

// ---------------- Kernel A (fused): blocks [0,512) = vertex1 ; blocks [512,2560) = build
__global__ __launch_bounds__(256) void k_front(
    const float* __restrict__ X, const float* __restrict__ Wv, const float* __restrict__ bv,
    const float* __restrict__ vW1, const float* __restrict__ vb1,
    const float* __restrict__ vW2, const float* __restrict__ vb2,
    const float* __restrict__ H,
    float* __restrict__ Xt, float* __restrict__ attn4,
    unsigned long long* __restrict__ Hbits, int* __restrict__ vdeg, int* __restrict__ vlist)
{
    __shared__ float Xs[2][8][CIN];
    int t = threadIdx.x;
    if (blockIdx.x < NV / 16) {
        // ---- vertex1: Xt = X@Wv+bv ; attn ----
        int half = t >> 7, tt = t & 127;
        int v0 = blockIdx.x * 16 + half * 8;
        for (int v = 0; v < 8; ++v) Xs[half][v][tt] = X[(size_t)(v0 + v) * CIN + tt];
        __syncthreads();

        float acc[8];
        float bvc = bv[tt];
#pragma unroll
        for (int v = 0; v < 8; ++v) acc[v] = bvc;
        for (int k = 0; k < CIN; ++k) {
            float w = Wv[k * COUT + tt];
#pragma unroll
            for (int v = 0; v < 8; ++v) acc[v] = fmaf(Xs[half][v][k], w, acc[v]);
        }
        for (int v = 0; v < 8; ++v) Xt[(size_t)(v0 + v) * COUT + tt] = acc[v];

        int h = tt >> 5, j = tt & 31;
        float hb = vb1[h * HID + j];
#pragma unroll
        for (int v = 0; v < 8; ++v) acc[v] = hb;
        for (int k = 0; k < CIN; ++k) {
            float w = vW1[(h * CIN + k) * HID + j];
#pragma unroll
            for (int v = 0; v < 8; ++v) acc[v] = fmaf(Xs[half][v][k], w, acc[v]);
        }
        float w2 = vW2[h * HID + j];
        float b2 = vb2[h];
        for (int v = 0; v < 8; ++v) {
            float val = gelu_f(acc[v]) * w2;
#pragma unroll
            for (int m = 16; m >= 1; m >>= 1) val += __shfl_xor(val, m, 64);
            if (j == 0) attn4[(size_t)(v0 + v) * NH + h] = sigmoid_f(val + b2);
        }
    } else {
        // ---- build: float4 H scan -> 16-bit lane masks -> Hbits words + vlist ----
        int b = blockIdx.x - NV / 16;
        int w = t >> 6;
        int lane = t & 63;
        int v = b * 4 + w;
        const float4* row4 = (const float4*)(H + (size_t)v * NE);
        int base = 0;
        int* vl = vlist + (size_t)v * VCAP;
#pragma unroll
        for (int it = 0; it < NE / 1024; ++it) {
            int e0 = it * 1024 + lane * 16;
            float4 f0 = row4[it * 256 + lane * 4 + 0];
            float4 f1 = row4[it * 256 + lane * 4 + 1];
            float4 f2 = row4[it * 256 + lane * 4 + 2];
            float4 f3 = row4[it * 256 + lane * 4 + 3];
            unsigned int m16 = 0;
            m16 |= (f0.x != 0.0f ? 1u : 0u) << 0;  m16 |= (f0.y != 0.0f ? 1u : 0u) << 1;
            m16 |= (f0.z != 0.0f ? 1u : 0u) << 2;  m16 |= (f0.w != 0.0f ? 1u : 0u) << 3;
            m16 |= (f1.x != 0.0f ? 1u : 0u) << 4;  m16 |= (f1.y != 0.0f ? 1u : 0u) << 5;
            m16 |= (f1.z != 0.0f ? 1u : 0u) << 6;  m16 |= (f1.w != 0.0f ? 1u : 0u) << 7;
            m16 |= (f2.x != 0.0f ? 1u : 0u) << 8;  m16 |= (f2.y != 0.0f ? 1u : 0u) << 9;
            m16 |= (f2.z != 0.0f ? 1u : 0u) << 10; m16 |= (f2.w != 0.0f ? 1u : 0u) << 11;
            m16 |= (f3.x != 0.0f ? 1u : 0u) << 12; m16 |= (f3.y != 0.0f ? 1u : 0u) << 13;
            m16 |= (f3.z != 0.0f ? 1u : 0u) << 14; m16 |= (f3.w != 0.0f ? 1u : 0u) << 15;

            int cnt = __popc(m16);
            int inc = cnt;
#pragma unroll
            for (int s = 1; s < 64; s <<= 1) {
                int y = __shfl_up(inc, s, 64);
                if (lane >= s) inc += y;
            }
            int tot = __shfl(inc, 63, 64);
            int q = lane & 15;
            unsigned int w0 = __shfl(m16, q * 4 + 0, 64);
            unsigned int w1 = __shfl(m16, q * 4 + 1, 64);
            unsigned int w2 = __shfl(m16, q * 4 + 2, 64);
            unsigned int w3 = __shfl(m16, q * 4 + 3, 64);
            if (lane < 16) {
                unsigned long long word = (unsigned long long)w0
                    | ((unsigned long long)w1 << 16)
                    | ((unsigned long long)w2 << 32)
                    | ((unsigned long long)w3 << 48);
                Hbits[(size_t)v * NWORDS + it * 16 + lane] = word;
            }
            int off = base + inc - cnt;
            unsigned int mm = m16;
            while (mm) {
                int j = __ffs(mm) - 1;
                mm &= mm - 1;
                if (off < VCAP) vl[off] = e0 + j;
                ++off;
            }
            base += tot;
        }
        if (lane == 0) vdeg[v] = base;
    }
}

// ---------------- Kernel 2b: bit-transpose Hbits[v][e-words] -> HbitsT[e][v-words]
__global__ __launch_bounds__(256) void k_transpose(
    const unsigned long long* __restrict__ Hbits, unsigned long long* __restrict__ HbitsT)
{
    __shared__ unsigned long long rows[64][NWORDS];   // 16 KB
    int t = threadIdx.x;
    int vt = blockIdx.x;
    for (int i = t; i < 64 * NWORDS; i += 256)
        rows[i >> 5][i & 31] = Hbits[(size_t)vt * 64 * NWORDS + i];
    __syncthreads();
    int wv = t >> 6;
    int lane = t & 63;
    const unsigned long long M[6] = {
        0xFFFFFFFF00000000ULL, 0xFFFF0000FFFF0000ULL, 0xFF00FF00FF00FF00ULL,
        0xF0F0F0F0F0F0F0F0ULL, 0xCCCCCCCCCCCCCCCCULL, 0xAAAAAAAAAAAAAAAAULL };
    const int js[6] = {32, 16, 8, 4, 2, 1};
#pragma unroll
    for (int itb = 0; itb < 8; ++itb) {
        int it = wv * 8 + itb;
        unsigned long long x = rows[lane][it];
#pragma unroll
        for (int s = 0; s < 6; ++s) {
            int j = js[s];
            unsigned long long y = __shfl_xor(x, j, 64);
            unsigned long long Ms = M[s];
            if ((lane & j) == 0) x = (x & ~Ms) | ((y << j) & Ms);
            else                 x = (x & Ms) | ((y >> j) & ~Ms);
        }
        HbitsT[(size_t)(it * 64 + lane) * TWORDS + vt] = x;
    }
}

// ---------------- Kernel 3a: per-edge aggregation ONLY. 1 edge/block, 256 thr, tiny LDS.
// Writes normalized ecat (E x 512) + out_att.
__global__ __launch_bounds__(256) void k_agg(
    const float* __restrict__ Xt, const float* __restrict__ attn4,
    const unsigned long long* __restrict__ HbitsT,
    float* __restrict__ ecat_g, float* __restrict__ out_att)
{
    __shared__ int lst[LCAP];          // 1 KB
    __shared__ int wsum[2];
    __shared__ float pt[4][NH][COUT];  // 8 KB
    __shared__ float asp[4];

    int t = threadIdx.x;
    int wid = t >> 6, lane = t & 63;
    int e = blockIdx.x;

    // membership: threads 0..127 read the bitmap row; all threads hit uniform barriers
    unsigned long long wd = 0ull;
    if (t < 128) wd = HbitsT[(size_t)e * TWORDS + t];
    int cnt = __popcll(wd);
    int inc = cnt;
#pragma unroll
    for (int s = 1; s < 64; s <<= 1) {
        int y = __shfl_up(inc, s, 64);
        if (lane >= s) inc += y;
    }
    if (lane == 63 && wid < 2) wsum[wid] = inc;
    __syncthreads();
    int n0 = wsum[0] + wsum[1];
    if (t < 128) {
        int base = (wid ? wsum[0] : 0) + inc - cnt;
        int vbase = t * 64;
        unsigned long long mm = wd;
        while (mm) {
            int i = __ffsll(mm) - 1;
            mm &= mm - 1;
            if (base < LCAP) lst[base] = vbase + i;
            ++base;
        }
    }
    __syncthreads();

    float inv = 1.0f / fmaxf((float)n0, 1.0f);
    int n = n0 < LCAP ? n0 : LCAP;

    // gather: 4 waves stride the member list; lane covers channels lane, lane+64
    float p00 = 0, p10 = 0, p20 = 0, p30 = 0;
    float p01 = 0, p11 = 0, p21 = 0, p31 = 0;
    float as = 0;
#pragma unroll 2
    for (int i = wid; i < n; i += 4) {
        int v = lst[i];
        float x0 = Xt[(size_t)v * COUT + lane];
        float x1 = Xt[(size_t)v * COUT + lane + 64];
        float4 a = *(const float4*)(attn4 + (size_t)v * NH);
        p00 = fmaf(x0, a.x, p00);  p01 = fmaf(x1, a.x, p01);
        p10 = fmaf(x0, a.y, p10);  p11 = fmaf(x1, a.y, p11);
        p20 = fmaf(x0, a.z, p20);  p21 = fmaf(x1, a.z, p21);
        p30 = fmaf(x0, a.w, p30);  p31 = fmaf(x1, a.w, p31);
        as += a.w;
    }
    pt[wid][0][lane] = p00;  pt[wid][0][lane + 64] = p01;
    pt[wid][1][lane] = p10;  pt[wid][1][lane + 64] = p11;
    pt[wid][2][lane] = p20;  pt[wid][2][lane + 64] = p21;
    pt[wid][3][lane] = p30;  pt[wid][3][lane + 64] = p31;
    if (lane == 0) asp[wid] = as;
    __syncthreads();

#pragma unroll
    for (int r = 0; r < 2; ++r) {
        int k = t + r * 256;
        int h = k >> 7, ch = k & 127;
        float s = pt[0][h][ch] + pt[1][h][ch] + pt[2][h][ch] + pt[3][h][ch];
        ecat_g[(size_t)e * 512 + k] = s * inv;
    }
    if (t == 0) out_att[e] = (asp[0] + asp[1] + asp[2] + asp[3]) * inv;
}

// ---------------- Kernel 3b: tiled combine: ef = ecat@Wc+bc, te = efr@We+be, score MLP,
// blend, LN, BN partials. 8 edges/block, 512 threads.
__global__ __launch_bounds__(512) void k_combine(
    const float* __restrict__ ecat_g, const float* __restrict__ edge_features,
    const float* __restrict__ Wc, const float* __restrict__ bc,
    const float* __restrict__ We, const float* __restrict__ be,
    const float* __restrict__ eW1, const float* __restrict__ eb1,
    const float* __restrict__ eW2, const float* __restrict__ eb2,
    const float* __restrict__ ln_g, const float* __restrict__ ln_b,
    float* __restrict__ e_ln, float* __restrict__ bn_sum, float* __restrict__ bn_sq)
{
    __shared__ float ecs[ETILE][512];   // 16 KB
    __shared__ float efr[ETILE][COUT];  // 4 KB
    __shared__ float efs[ETILE][COUT];  // 4 KB
    __shared__ float teL[ETILE][COUT];  // 4 KB
    __shared__ float yb[ETILE][COUT];   // 4 KB
    __shared__ float ews[ETILE];
    __shared__ float red[ETILE][2][2];

    int t = threadIdx.x;
    int e0 = blockIdx.x * ETILE;
    int eslot = t >> 7, c = t & 127;
    int lane = t & 63;
    int gw = (t >> 6) & 1;

    for (int idx = t; idx < ETILE * 512; idx += 512)
        ecs[idx >> 9][idx & 511] = ecat_g[(size_t)e0 * 512 + idx];
    for (int idx = t; idx < ETILE * COUT; idx += 512)
        efr[idx >> 7][idx & 127] = edge_features[(size_t)e0 * COUT + idx];
    __syncthreads();

    float accW0 = 0, accW1 = 0;
    for (int k = 0; k < 512; ++k) {
        float w = Wc[(size_t)k * COUT + c];
        accW0 = fmaf(ecs[eslot][k], w, accW0);
        accW1 = fmaf(ecs[eslot + 4][k], w, accW1);
    }
    float accT0 = 0, accT1 = 0;
    for (int k = 0; k < COUT; ++k) {
        float w = We[(size_t)k * COUT + c];
        accT0 = fmaf(efr[eslot][k], w, accT0);
        accT1 = fmaf(efr[eslot + 4][k], w, accT1);
    }
    float bcc = bc[c], bec = be[c];
    efs[eslot][c] = accW0 + bcc;
    efs[eslot + 4][c] = accW1 + bcc;
    teL[eslot][c] = accT0 + bec;
    teL[eslot + 4][c] = accT1 + bec;
    __syncthreads();

    // score MLP: 8 edges x 32 hidden = 256 threads
    if (t < ETILE * 32) {
        int ee = t >> 5, j = t & 31;
        float hj = eb1[j];
        for (int k = 0; k < COUT; ++k) hj = fmaf(efs[ee][k], eW1[k * HID + j], hj);
        float val = gelu_f(hj) * eW2[j];
#pragma unroll
        for (int m = 16; m >= 1; m >>= 1) val += __shfl_xor(val, m, 32);
        if (j == 0) ews[ee] = sigmoid_f(val + eb2[0]);
    }
    __syncthreads();

    // blend + LN per edge (each thread handles edges eslot and eslot+4)
#pragma unroll
    for (int j = 0; j < 2; ++j) {
        int e = eslot + 4 * j;
        float ew = ews[e];
        float x = efs[e][c] * ew + teL[e][c] * (1.0f - ew);
        float s = x, q = x * x;
#pragma unroll
        for (int m = 32; m >= 1; m >>= 1) { s += __shfl_xor(s, m, 64); q += __shfl_xor(q, m, 64); }
        if (lane == 0) { red[e][gw][0] = s; red[e][gw][1] = q; }
        __syncthreads();
        float S = red[e][0][0] + red[e][1][0];
        float Q = red[e][0][1] + red[e][1][1];
        float m_ = S * (1.0f / COUT);
        float var = Q * (1.0f / COUT) - m_ * m_;
        float y = (x - m_) * rsqrtf(var + EPSV) * ln_g[c] + ln_b[c];
        e_ln[(size_t)(e0 + e) * COUT + c] = y;
        yb[e][c] = y;
        __syncthreads();
    }

    if (t < 128) {
        float s = 0, q = 0;
#pragma unroll
        for (int e = 0; e < ETILE; ++e) { float y = yb[e][t]; s += y; q += y * y; }
        atomicAdd(&bn_sum[t], s);
        atomicAdd(&bn_sq[t], q);
    }
}

// ---------------- Kernel 5: BN apply -> out_e (gelu) only
__global__ __launch_bounds__(256) void k_bnapply(const float* __restrict__ e_ln,
    const float* __restrict__ bn_sum, const float* __restrict__ bn_sq,
    const float* __restrict__ bn_g, const float* __restrict__ bn_b,
    float* __restrict__ out_e)
{
    int idx = blockIdx.x * 256 + threadIdx.x;
    int c = idx & 127;
    float m = bn_sum[c] * (1.0f / NE);
    float var = bn_sq[c] * (1.0f / NE) - m * m;
    float x = e_ln[idx];
    float y = (x - m) * rsqrtf(var + EPSV) * bn_g[c] + bn_b[c];
    out_e[idx] = gelu_f(y);
}

// ---------------- Kernel 6: e2v gather (BN folded: A*sum + n*B) + gate GEMM (split-K,
// weights shared across 8 vertices) + LN + residual + gelu. 512 thr, 8 vertices/block.
__global__ __launch_bounds__(512) void k_vertex2(
    const float* __restrict__ X, const int* __restrict__ vdeg, const int* __restrict__ vlist,
    const float* __restrict__ e_ln,
    const float* __restrict__ bn_sum, const float* __restrict__ bn_sq,
    const float* __restrict__ bn_g, const float* __restrict__ bn_b,
    const float* __restrict__ Xt,
    const float* __restrict__ Wg, const float* __restrict__ bg,
    const float* __restrict__ ln_g, const float* __restrict__ ln_b,
    float* __restrict__ out_v)
{
    __shared__ float XsF[8 * CIN];     // 4 KB
    __shared__ float vfF[8 * COUT];    // 4 KB
    __shared__ int lst[8][VCAP];       // 3 KB
    __shared__ int degs[8];
    __shared__ float part[4 * 8 * COUT]; // 16 KB
    __shared__ float red[8][2][2];

    int t = threadIdx.x;
    int vg = t >> 6, lane = t & 63;
    int g4 = t >> 7, c = t & 127;
    int gw2 = (t >> 6) & 1;
    int v0 = blockIdx.x * 8;

    {
        float2 x2 = *(const float2*)(X + (size_t)(v0 + vg) * CIN + lane * 2);
        XsF[vg * CIN + lane * 2] = x2.x;
        XsF[vg * CIN + lane * 2 + 1] = x2.y;
    }
    for (int i = t; i < 8 * VCAP; i += 512)
        lst[i / VCAP][i % VCAP] = vlist[(size_t)v0 * VCAP + i];
    if (t < 8) degs[t] = vdeg[v0 + t];
    __syncthreads();

    int ch0 = lane * 2;
    float m0 = bn_sum[ch0] * (1.0f / NE);
    float m1 = bn_sum[ch0 + 1] * (1.0f / NE);
    float A0 = bn_g[ch0] * rsqrtf(bn_sq[ch0] * (1.0f / NE) - m0 * m0 + EPSV);
    float A1 = bn_g[ch0 + 1] * rsqrtf(bn_sq[ch0 + 1] * (1.0f / NE) - m1 * m1 + EPSV);
    float B0 = bn_b[ch0] - m0 * A0;
    float B1 = bn_b[ch0 + 1] - m1 * A1;

    int n = degs[vg];
    if (n > VCAP) n = VCAP;
    float sx = 0, sy = 0;
    for (int i = 0; i < n; ++i) {
        float2 v2 = *(const float2*)(e_ln + (size_t)lst[vg][i] * COUT + ch0);
        sx += v2.x;
        sy += v2.y;
    }
    float fn = (float)n;
    vfF[vg * COUT + ch0] = A0 * sx + fn * B0;
    vfF[vg * COUT + ch0 + 1] = A1 * sy + fn * B1;
    __syncthreads();

    {
        float accW[8] = {0, 0, 0, 0, 0, 0, 0, 0};
        const float* wp = Wg + (size_t)(g4 * 64) * COUT + c;
        const float* src = (g4 < 2) ? XsF : vfF;
        int kb = (g4 & 1) * 64;
        for (int ki = 0; ki < 64; ++ki) {
            float w = wp[(size_t)ki * COUT];
#pragma unroll
            for (int v = 0; v < 8; ++v)
                accW[v] = fmaf(src[v * 128 + kb + ki], w, accW[v]);
        }
#pragma unroll
        for (int v = 0; v < 8; ++v) part[g4 * 1024 + v * COUT + c] = accW[v];
    }
    __syncthreads();

    float xv[2];
#pragma unroll
    for (int rep = 0; rep < 2; ++rep) {
        int v = g4 + rep * 4;
        float ag = part[0 * 1024 + v * COUT + c] + part[1 * 1024 + v * COUT + c]
                 + part[2 * 1024 + v * COUT + c] + part[3 * 1024 + v * COUT + c] + bg[c];
        float gate = sigmoid_f(ag);
        float x = gate * vfF[v * COUT + c] + (1.0f - gate) * Xt[(size_t)(v0 + v) * COUT + c];
        xv[rep] = x;
        float s = x, q = x * x;
#pragma unroll
        for (int m = 32; m >= 1; m >>= 1) { s += __shfl_xor(s, m, 64); q += __shfl_xor(q, m, 64); }
        if (lane == 0) { red[v][gw2][0] = s; red[v][gw2][1] = q; }
    }
    __syncthreads();
#pragma unroll
    for (int rep = 0; rep < 2; ++rep) {
        int v = g4 + rep * 4;
        float S = red[v][0][0] + red[v][1][0];
        float Q = red[v][0][1] + red[v][1][1];
        float m_ = S * (1.0f / COUT);
        float var = Q * (1.0f / COUT) - m_ * m_;
        float y = (xv[rep] - m_) * rsqrtf(var + EPSV) * ln_g[c] + ln_b[c];
        y = y + XsF[v * CIN + c];
        out_v[(size_t)(v0 + v) * COUT + c] = gelu_f(y);
    }
}

extern "C" void kernel_launch(void* const* d_in, const int* in_sizes, int n_in,
                              void* d_out, int out_size, void* d_ws, size_t ws_size,
                              hipStream_t stream) {
    const float* X    = (const float*)d_in[0];
    const float* H    = (const float*)d_in[1];
    const float* edge_features = (const float*)d_in[2];
    const float* Wv   = (const float*)d_in[3];
    const float* bv   = (const float*)d_in[4];
    const float* We   = (const float*)d_in[5];
    const float* be   = (const float*)d_in[6];
    const float* vW1  = (const float*)d_in[7];
    const float* vb1  = (const float*)d_in[8];
    const float* vW2  = (const float*)d_in[9];
    const float* vb2  = (const float*)d_in[10];
    const float* eW1  = (const float*)d_in[11];
    const float* eb1  = (const float*)d_in[12];
    const float* eW2  = (const float*)d_in[13];
    const float* eb2  = (const float*)d_in[14];
    const float* Wc   = (const float*)d_in[15];
    const float* bc   = (const float*)d_in[16];
    const float* ln_e_g = (const float*)d_in[17];
    const float* ln_e_b = (const float*)d_in[18];
    const float* ln_v_g = (const float*)d_in[19];
    const float* ln_v_b = (const float*)d_in[20];
    const float* bn_g = (const float*)d_in[21];
    const float* bn_b = (const float*)d_in[22];
    const float* Wg   = (const float*)d_in[23];
    const float* bg   = (const float*)d_in[24];

    float* out_v  = (float*)d_out;            // V*COUT
    float* out_e  = out_v + NV * COUT;        // E*COUT
    float* out_att = out_e + NE * COUT;       // E

    char* w = (char*)d_ws;
    float* Xt     = (float*)w; w += (size_t)NV * COUT * 4;
    float* attn4  = (float*)w; w += (size_t)NV * NH * 4;
    float* e_ln   = (float*)w; w += (size_t)NE * COUT * 4;
    float* ecat_g = (float*)w; w += (size_t)NE * NH * COUT * 4;
    float* bn_sum = (float*)w; w += COUT * 4;
    float* bn_sq  = (float*)w; w += COUT * 4;
    int*   vdeg   = (int*)w;   w += (size_t)NV * 4;
    int*   vlist  = (int*)w;   w += (size_t)NV * VCAP * 4;
    unsigned long long* Hbits  = (unsigned long long*)w; w += (size_t)NV * NWORDS * 8;
    unsigned long long* HbitsT = (unsigned long long*)w; w += (size_t)NE * TWORDS * 8;

    hipMemsetAsync(bn_sum, 0, 2 * COUT * sizeof(float), stream);

    k_front<<<NV / 16 + NV / 4, 256, 0, stream>>>(X, Wv, bv, vW1, vb1, vW2, vb2, H,
                                                  Xt, attn4, Hbits, vdeg, vlist);
    k_transpose<<<NV / 64, 256, 0, stream>>>(Hbits, HbitsT);
    k_agg<<<NE, 256, 0, stream>>>(Xt, attn4, HbitsT, ecat_g, out_att);
    k_combine<<<NE / ETILE, 512, 0, stream>>>(ecat_g, edge_features,
                                              Wc, bc, We, be, eW1, eb1, eW2, eb2,
                                              ln_e_g, ln_e_b, e_ln, bn_sum, bn_sq);
    k_bnapply<<<(NE * COUT) / 256, 256, 0, stream>>>(e_ln, bn_sum, bn_sq, bn_g, bn_b, out_e);
    k_vertex2<<<NV / 8, 512, 0, stream>>>(X, vdeg, vlist, e_ln, bn_sum, bn_sq, bn_g, bn_b,
                                          Xt, Wg, bg, ln_v_g, ln_v_b, out_v);
}

// Round 11
// 258.413 us; speedup vs baseline: 1.0428x; 1.0428x over previous
//
#include <hip/hip_runtime.h>
#include <hip/hip_bf16.h>
#include <math.h>

#define NV 8192
#define NE 2048
#define CIN 128
#define COUT 128
#define NH 4
#define HID 32
#define ETILE 8
#define LCAP 256
#define VCAP 96
#define NWORDS (NE / 64)
#define TWORDS (NV / 64)
#define EPSV 1e-5f

__device__ __forceinline__ float gelu_f(float x) {
    return 0.5f * x * (1.0f + erff(x * 0.70710678118654752f));
}
__device__ __forceinline__ float sigmoid_f(float x) {
    return 1.0f / (1.0f + expf(-x));
}

// ---------------- Kernel A (fused): blocks [0,512) = vertex1 ; blocks [512,2560) = build
__global__ __launch_bounds__(256) void k_front(
    const float* __restrict__ X, const float* __restrict__ Wv, const float* __restrict__ bv,
    const float* __restrict__ vW1, const float* __restrict__ vb1,
    const float* __restrict__ vW2, const float* __restrict__ vb2,
    const float* __restrict__ H,
    float* __restrict__ Xt, float* __restrict__ attn4,
    unsigned long long* __restrict__ Hbits, int* __restrict__ vdeg, int* __restrict__ vlist)
{
    __shared__ float Xs[2][8][CIN];
    int t = threadIdx.x;
    if (blockIdx.x < NV / 16) {
        // ---- vertex1: Xt = X@Wv+bv ; attn ----
        int half = t >> 7, tt = t & 127;
        int v0 = blockIdx.x * 16 + half * 8;
        for (int v = 0; v < 8; ++v) Xs[half][v][tt] = X[(size_t)(v0 + v) * CIN + tt];
        __syncthreads();

        float acc[8];
        float bvc = bv[tt];
#pragma unroll
        for (int v = 0; v < 8; ++v) acc[v] = bvc;
        for (int k = 0; k < CIN; ++k) {
            float w = Wv[k * COUT + tt];
#pragma unroll
            for (int v = 0; v < 8; ++v) acc[v] = fmaf(Xs[half][v][k], w, acc[v]);
        }
        for (int v = 0; v < 8; ++v) Xt[(size_t)(v0 + v) * COUT + tt] = acc[v];

        int h = tt >> 5, j = tt & 31;
        float hb = vb1[h * HID + j];
#pragma unroll
        for (int v = 0; v < 8; ++v) acc[v] = hb;
        for (int k = 0; k < CIN; ++k) {
            float w = vW1[(h * CIN + k) * HID + j];
#pragma unroll
            for (int v = 0; v < 8; ++v) acc[v] = fmaf(Xs[half][v][k], w, acc[v]);
        }
        float w2 = vW2[h * HID + j];
        float b2 = vb2[h];
        for (int v = 0; v < 8; ++v) {
            float val = gelu_f(acc[v]) * w2;
#pragma unroll
            for (int m = 16; m >= 1; m >>= 1) val += __shfl_xor(val, m, 64);
            if (j == 0) attn4[(size_t)(v0 + v) * NH + h] = sigmoid_f(val + b2);
        }
    } else {
        // ---- build: float4 H scan -> 16-bit lane masks -> Hbits words + vlist ----
        int b = blockIdx.x - NV / 16;
        int w = t >> 6;
        int lane = t & 63;
        int v = b * 4 + w;
        const float4* row4 = (const float4*)(H + (size_t)v * NE);
        int base = 0;
        int* vl = vlist + (size_t)v * VCAP;
#pragma unroll
        for (int it = 0; it < NE / 1024; ++it) {
            int e0 = it * 1024 + lane * 16;
            float4 f0 = row4[it * 256 + lane * 4 + 0];
            float4 f1 = row4[it * 256 + lane * 4 + 1];
            float4 f2 = row4[it * 256 + lane * 4 + 2];
            float4 f3 = row4[it * 256 + lane * 4 + 3];
            unsigned int m16 = 0;
            m16 |= (f0.x != 0.0f ? 1u : 0u) << 0;  m16 |= (f0.y != 0.0f ? 1u : 0u) << 1;
            m16 |= (f0.z != 0.0f ? 1u : 0u) << 2;  m16 |= (f0.w != 0.0f ? 1u : 0u) << 3;
            m16 |= (f1.x != 0.0f ? 1u : 0u) << 4;  m16 |= (f1.y != 0.0f ? 1u : 0u) << 5;
            m16 |= (f1.z != 0.0f ? 1u : 0u) << 6;  m16 |= (f1.w != 0.0f ? 1u : 0u) << 7;
            m16 |= (f2.x != 0.0f ? 1u : 0u) << 8;  m16 |= (f2.y != 0.0f ? 1u : 0u) << 9;
            m16 |= (f2.z != 0.0f ? 1u : 0u) << 10; m16 |= (f2.w != 0.0f ? 1u : 0u) << 11;
            m16 |= (f3.x != 0.0f ? 1u : 0u) << 12; m16 |= (f3.y != 0.0f ? 1u : 0u) << 13;
            m16 |= (f3.z != 0.0f ? 1u : 0u) << 14; m16 |= (f3.w != 0.0f ? 1u : 0u) << 15;

            int cnt = __popc(m16);
            int inc = cnt;
#pragma unroll
            for (int s = 1; s < 64; s <<= 1) {
                int y = __shfl_up(inc, s, 64);
                if (lane >= s) inc += y;
            }
            int tot = __shfl(inc, 63, 64);
            int q = lane & 15;
            unsigned int w0 = __shfl(m16, q * 4 + 0, 64);
            unsigned int w1 = __shfl(m16, q * 4 + 1, 64);
            unsigned int w2 = __shfl(m16, q * 4 + 2, 64);
            unsigned int w3 = __shfl(m16, q * 4 + 3, 64);
            if (lane < 16) {
                unsigned long long word = (unsigned long long)w0
                    | ((unsigned long long)w1 << 16)
                    | ((unsigned long long)w2 << 32)
                    | ((unsigned long long)w3 << 48);
                Hbits[(size_t)v * NWORDS + it * 16 + lane] = word;
            }
            int off = base + inc - cnt;
            unsigned int mm = m16;
            while (mm) {
                int j = __ffs(mm) - 1;
                mm &= mm - 1;
                if (off < VCAP) vl[off] = e0 + j;
                ++off;
            }
            base += tot;
        }
        if (lane == 0) vdeg[v] = base;
    }
}

// ---------------- Kernel 2b: bit-transpose Hbits[v][e-words] -> HbitsT[e][v-words]
__global__ __launch_bounds__(256) void k_transpose(
    const unsigned long long* __restrict__ Hbits, unsigned long long* __restrict__ HbitsT)
{
    __shared__ unsigned long long rows[64][NWORDS];   // 16 KB
    int t = threadIdx.x;
    int vt = blockIdx.x;
    for (int i = t; i < 64 * NWORDS; i += 256)
        rows[i >> 5][i & 31] = Hbits[(size_t)vt * 64 * NWORDS + i];
    __syncthreads();
    int wv = t >> 6;
    int lane = t & 63;
    const unsigned long long M[6] = {
        0xFFFFFFFF00000000ULL, 0xFFFF0000FFFF0000ULL, 0xFF00FF00FF00FF00ULL,
        0xF0F0F0F0F0F0F0F0ULL, 0xCCCCCCCCCCCCCCCCULL, 0xAAAAAAAAAAAAAAAAULL };
    const int js[6] = {32, 16, 8, 4, 2, 1};
#pragma unroll
    for (int itb = 0; itb < 8; ++itb) {
        int it = wv * 8 + itb;
        unsigned long long x = rows[lane][it];
#pragma unroll
        for (int s = 0; s < 6; ++s) {
            int j = js[s];
            unsigned long long y = __shfl_xor(x, j, 64);
            unsigned long long Ms = M[s];
            if ((lane & j) == 0) x = (x & ~Ms) | ((y << j) & Ms);
            else                 x = (x & Ms) | ((y >> j) & ~Ms);
        }
        HbitsT[(size_t)(it * 64 + lane) * TWORDS + vt] = x;
    }
}

// ---------------- Kernel 3a: per-edge aggregation ONLY. 1 edge/block, 256 thr, tiny LDS.
__global__ __launch_bounds__(256) void k_agg(
    const float* __restrict__ Xt, const float* __restrict__ attn4,
    const unsigned long long* __restrict__ HbitsT,
    float* __restrict__ ecat_g, float* __restrict__ out_att)
{
    __shared__ int lst[LCAP];          // 1 KB
    __shared__ int wsum[2];
    __shared__ float pt[4][NH][COUT];  // 8 KB
    __shared__ float asp[4];

    int t = threadIdx.x;
    int wid = t >> 6, lane = t & 63;
    int e = blockIdx.x;

    unsigned long long wd = 0ull;
    if (t < 128) wd = HbitsT[(size_t)e * TWORDS + t];
    int cnt = __popcll(wd);
    int inc = cnt;
#pragma unroll
    for (int s = 1; s < 64; s <<= 1) {
        int y = __shfl_up(inc, s, 64);
        if (lane >= s) inc += y;
    }
    if (lane == 63 && wid < 2) wsum[wid] = inc;
    __syncthreads();
    int n0 = wsum[0] + wsum[1];
    if (t < 128) {
        int base = (wid ? wsum[0] : 0) + inc - cnt;
        int vbase = t * 64;
        unsigned long long mm = wd;
        while (mm) {
            int i = __ffsll(mm) - 1;
            mm &= mm - 1;
            if (base < LCAP) lst[base] = vbase + i;
            ++base;
        }
    }
    __syncthreads();

    float inv = 1.0f / fmaxf((float)n0, 1.0f);
    int n = n0 < LCAP ? n0 : LCAP;

    float p00 = 0, p10 = 0, p20 = 0, p30 = 0;
    float p01 = 0, p11 = 0, p21 = 0, p31 = 0;
    float as = 0;
#pragma unroll 2
    for (int i = wid; i < n; i += 4) {
        int v = lst[i];
        float x0 = Xt[(size_t)v * COUT + lane];
        float x1 = Xt[(size_t)v * COUT + lane + 64];
        float4 a = *(const float4*)(attn4 + (size_t)v * NH);
        p00 = fmaf(x0, a.x, p00);  p01 = fmaf(x1, a.x, p01);
        p10 = fmaf(x0, a.y, p10);  p11 = fmaf(x1, a.y, p11);
        p20 = fmaf(x0, a.z, p20);  p21 = fmaf(x1, a.z, p21);
        p30 = fmaf(x0, a.w, p30);  p31 = fmaf(x1, a.w, p31);
        as += a.w;
    }
    pt[wid][0][lane] = p00;  pt[wid][0][lane + 64] = p01;
    pt[wid][1][lane] = p10;  pt[wid][1][lane + 64] = p11;
    pt[wid][2][lane] = p20;  pt[wid][2][lane + 64] = p21;
    pt[wid][3][lane] = p30;  pt[wid][3][lane + 64] = p31;
    if (lane == 0) asp[wid] = as;
    __syncthreads();

#pragma unroll
    for (int r = 0; r < 2; ++r) {
        int k = t + r * 256;
        int h = k >> 7, ch = k & 127;
        float s = pt[0][h][ch] + pt[1][h][ch] + pt[2][h][ch] + pt[3][h][ch];
        ecat_g[(size_t)e * 512 + k] = s * inv;
    }
    if (t == 0) out_att[e] = (asp[0] + asp[1] + asp[2] + asp[3]) * inv;
}

// ---------------- Kernel 3b-1: split-K partials for ef = ecat@Wc and te = efr@We.
// Grid = (NE/ETILE) x 4 slices; 256 thr; each thread: c, K-half, 8 edges in registers.
__global__ __launch_bounds__(256) void k_cpart(
    const float* __restrict__ ecat_g, const float* __restrict__ edge_features,
    const float* __restrict__ Wc, const float* __restrict__ We,
    float* __restrict__ efp, float* __restrict__ tep)
{
    __shared__ float ecs[ETILE][128];   // 4 KB  (this slice's K-range)
    __shared__ float efr8[ETILE][32];   // 1 KB
    __shared__ float part[2][ETILE][128]; // 8 KB

    int t = threadIdx.x;
    int s = blockIdx.x & 3;             // K-slice
    int eb = blockIdx.x >> 2;
    int e0 = eb * ETILE;
    int c = t & 127, h = t >> 7;

    for (int idx = t; idx < ETILE * 128; idx += 256) {
        int e = idx >> 7, k = idx & 127;
        ecs[e][k] = ecat_g[(size_t)(e0 + e) * 512 + s * 128 + k];
    }
    if (t < ETILE * 32) {
        int e = t >> 5, k = t & 31;
        efr8[e][k] = edge_features[(size_t)(e0 + e) * COUT + s * 32 + k];
    }
    __syncthreads();

    // Wc slice: K-half h covers kk in [h*64, h*64+64)
    float accW[ETILE] = {0, 0, 0, 0, 0, 0, 0, 0};
    {
        const float* wp = Wc + (size_t)(s * 128 + h * 64) * COUT + c;
        for (int kk = 0; kk < 64; ++kk) {
            float w = wp[(size_t)kk * COUT];
            int k = h * 64 + kk;
#pragma unroll
            for (int e = 0; e < ETILE; ++e)
                accW[e] = fmaf(ecs[e][k], w, accW[e]);
        }
    }
#pragma unroll
    for (int e = 0; e < ETILE; ++e) part[h][e][c] = accW[e];
    __syncthreads();
    if (h == 0) {
#pragma unroll
        for (int e = 0; e < ETILE; ++e)
            efp[(size_t)s * NE * COUT + (size_t)(e0 + e) * COUT + c] =
                part[0][e][c] + part[1][e][c];
    }
    __syncthreads();

    // We slice: K-half h covers kk in [h*16, h*16+16)
    float accT[ETILE] = {0, 0, 0, 0, 0, 0, 0, 0};
    {
        const float* wt = We + (size_t)(s * 32 + h * 16) * COUT + c;
        for (int kk = 0; kk < 16; ++kk) {
            float w = wt[(size_t)kk * COUT];
            int k = h * 16 + kk;
#pragma unroll
            for (int e = 0; e < ETILE; ++e)
                accT[e] = fmaf(efr8[e][k], w, accT[e]);
        }
    }
#pragma unroll
    for (int e = 0; e < ETILE; ++e) part[h][e][c] = accT[e];
    __syncthreads();
    if (h == 0) {
#pragma unroll
        for (int e = 0; e < ETILE; ++e)
            tep[(size_t)s * NE * COUT + (size_t)(e0 + e) * COUT + c] =
                part[0][e][c] + part[1][e][c];
    }
}

// ---------------- Kernel 3b-2: reduce partials + score MLP + blend + LN + BN partials.
__global__ __launch_bounds__(512) void k_cred(
    const float* __restrict__ efp, const float* __restrict__ tep,
    const float* __restrict__ bc, const float* __restrict__ be,
    const float* __restrict__ eW1, const float* __restrict__ eb1,
    const float* __restrict__ eW2, const float* __restrict__ eb2,
    const float* __restrict__ ln_g, const float* __restrict__ ln_b,
    float* __restrict__ e_ln, float* __restrict__ bn_sum, float* __restrict__ bn_sq)
{
    __shared__ float efs[ETILE][COUT];  // 4 KB
    __shared__ float teL[ETILE][COUT];  // 4 KB
    __shared__ float yb[ETILE][COUT];   // 4 KB
    __shared__ float ews[ETILE];
    __shared__ float red[ETILE][2][2];

    int t = threadIdx.x;
    int e0 = blockIdx.x * ETILE;
    int eslot = t >> 7, c = t & 127;
    int lane = t & 63;
    int gw = (t >> 6) & 1;

#pragma unroll
    for (int j = 0; j < 2; ++j) {
        int e = eslot + 4 * j;
        size_t off = (size_t)(e0 + e) * COUT + c;
        float ef = bc[c], te = be[c];
#pragma unroll
        for (int s = 0; s < 4; ++s) {
            ef += efp[(size_t)s * NE * COUT + off];
            te += tep[(size_t)s * NE * COUT + off];
        }
        efs[e][c] = ef;
        teL[e][c] = te;
    }
    __syncthreads();

    // score MLP: 8 edges x 32 hidden = 256 threads
    if (t < ETILE * 32) {
        int ee = t >> 5, j = t & 31;
        float hj = eb1[j];
        for (int k = 0; k < COUT; ++k) hj = fmaf(efs[ee][k], eW1[k * HID + j], hj);
        float val = gelu_f(hj) * eW2[j];
#pragma unroll
        for (int m = 16; m >= 1; m >>= 1) val += __shfl_xor(val, m, 32);
        if (j == 0) ews[ee] = sigmoid_f(val + eb2[0]);
    }
    __syncthreads();

    // blend + LN per edge (each thread handles edges eslot and eslot+4)
#pragma unroll
    for (int j = 0; j < 2; ++j) {
        int e = eslot + 4 * j;
        float ew = ews[e];
        float x = efs[e][c] * ew + teL[e][c] * (1.0f - ew);
        float s = x, q = x * x;
#pragma unroll
        for (int m = 32; m >= 1; m >>= 1) { s += __shfl_xor(s, m, 64); q += __shfl_xor(q, m, 64); }
        if (lane == 0) { red[e][gw][0] = s; red[e][gw][1] = q; }
        __syncthreads();
        float S = red[e][0][0] + red[e][1][0];
        float Q = red[e][0][1] + red[e][1][1];
        float m_ = S * (1.0f / COUT);
        float var = Q * (1.0f / COUT) - m_ * m_;
        float y = (x - m_) * rsqrtf(var + EPSV) * ln_g[c] + ln_b[c];
        e_ln[(size_t)(e0 + e) * COUT + c] = y;
        yb[e][c] = y;
        __syncthreads();
    }

    if (t < 128) {
        float s = 0, q = 0;
#pragma unroll
        for (int e = 0; e < ETILE; ++e) { float y = yb[e][t]; s += y; q += y * y; }
        atomicAdd(&bn_sum[t], s);
        atomicAdd(&bn_sq[t], q);
    }
}

// ---------------- Kernel 5: BN apply -> out_e (gelu) only
__global__ __launch_bounds__(256) void k_bnapply(const float* __restrict__ e_ln,
    const float* __restrict__ bn_sum, const float* __restrict__ bn_sq,
    const float* __restrict__ bn_g, const float* __restrict__ bn_b,
    float* __restrict__ out_e)
{
    int idx = blockIdx.x * 256 + threadIdx.x;
    int c = idx & 127;
    float m = bn_sum[c] * (1.0f / NE);
    float var = bn_sq[c] * (1.0f / NE) - m * m;
    float x = e_ln[idx];
    float y = (x - m) * rsqrtf(var + EPSV) * bn_g[c] + bn_b[c];
    out_e[idx] = gelu_f(y);
}

// ---------------- Kernel 6: e2v gather (BN folded) + gate GEMM + LN + residual + gelu.
__global__ __launch_bounds__(512) void k_vertex2(
    const float* __restrict__ X, const int* __restrict__ vdeg, const int* __restrict__ vlist,
    const float* __restrict__ e_ln,
    const float* __restrict__ bn_sum, const float* __restrict__ bn_sq,
    const float* __restrict__ bn_g, const float* __restrict__ bn_b,
    const float* __restrict__ Xt,
    const float* __restrict__ Wg, const float* __restrict__ bg,
    const float* __restrict__ ln_g, const float* __restrict__ ln_b,
    float* __restrict__ out_v)
{
    __shared__ float XsF[8 * CIN];     // 4 KB
    __shared__ float vfF[8 * COUT];    // 4 KB
    __shared__ int lst[8][VCAP];       // 3 KB
    __shared__ int degs[8];
    __shared__ float part[4 * 8 * COUT]; // 16 KB
    __shared__ float red[8][2][2];

    int t = threadIdx.x;
    int vg = t >> 6, lane = t & 63;
    int g4 = t >> 7, c = t & 127;
    int gw2 = (t >> 6) & 1;
    int v0 = blockIdx.x * 8;

    {
        float2 x2 = *(const float2*)(X + (size_t)(v0 + vg) * CIN + lane * 2);
        XsF[vg * CIN + lane * 2] = x2.x;
        XsF[vg * CIN + lane * 2 + 1] = x2.y;
    }
    for (int i = t; i < 8 * VCAP; i += 512)
        lst[i / VCAP][i % VCAP] = vlist[(size_t)v0 * VCAP + i];
    if (t < 8) degs[t] = vdeg[v0 + t];
    __syncthreads();

    int ch0 = lane * 2;
    float m0 = bn_sum[ch0] * (1.0f / NE);
    float m1 = bn_sum[ch0 + 1] * (1.0f / NE);
    float A0 = bn_g[ch0] * rsqrtf(bn_sq[ch0] * (1.0f / NE) - m0 * m0 + EPSV);
    float A1 = bn_g[ch0 + 1] * rsqrtf(bn_sq[ch0 + 1] * (1.0f / NE) - m1 * m1 + EPSV);
    float B0 = bn_b[ch0] - m0 * A0;
    float B1 = bn_b[ch0 + 1] - m1 * A1;

    int n = degs[vg];
    if (n > VCAP) n = VCAP;
    float sx = 0, sy = 0;
    for (int i = 0; i < n; ++i) {
        float2 v2 = *(const float2*)(e_ln + (size_t)lst[vg][i] * COUT + ch0);
        sx += v2.x;
        sy += v2.y;
    }
    float fn = (float)n;
    vfF[vg * COUT + ch0] = A0 * sx + fn * B0;
    vfF[vg * COUT + ch0 + 1] = A1 * sy + fn * B1;
    __syncthreads();

    {
        float accW[8] = {0, 0, 0, 0, 0, 0, 0, 0};
        const float* wp = Wg + (size_t)(g4 * 64) * COUT + c;
        const float* src = (g4 < 2) ? XsF : vfF;
        int kb = (g4 & 1) * 64;
        for (int ki = 0; ki < 64; ++ki) {
            float w = wp[(size_t)ki * COUT];
#pragma unroll
            for (int v = 0; v < 8; ++v)
                accW[v] = fmaf(src[v * 128 + kb + ki], w, accW[v]);
        }
#pragma unroll
        for (int v = 0; v < 8; ++v) part[g4 * 1024 + v * COUT + c] = accW[v];
    }
    __syncthreads();

    float xv[2];
#pragma unroll
    for (int rep = 0; rep < 2; ++rep) {
        int v = g4 + rep * 4;
        float ag = part[0 * 1024 + v * COUT + c] + part[1 * 1024 + v * COUT + c]
                 + part[2 * 1024 + v * COUT + c] + part[3 * 1024 + v * COUT + c] + bg[c];
        float gate = sigmoid_f(ag);
        float x = gate * vfF[v * COUT + c] + (1.0f - gate) * Xt[(size_t)(v0 + v) * COUT + c];
        xv[rep] = x;
        float s = x, q = x * x;
#pragma unroll
        for (int m = 32; m >= 1; m >>= 1) { s += __shfl_xor(s, m, 64); q += __shfl_xor(q, m, 64); }
        if (lane == 0) { red[v][gw2][0] = s; red[v][gw2][1] = q; }
    }
    __syncthreads();
#pragma unroll
    for (int rep = 0; rep < 2; ++rep) {
        int v = g4 + rep * 4;
        float S = red[v][0][0] + red[v][1][0];
        float Q = red[v][0][1] + red[v][1][1];
        float m_ = S * (1.0f / COUT);
        float var = Q * (1.0f / COUT) - m_ * m_;
        float y = (xv[rep] - m_) * rsqrtf(var + EPSV) * ln_g[c] + ln_b[c];
        y = y + XsF[v * CIN + c];
        out_v[(size_t)(v0 + v) * COUT + c] = gelu_f(y);
    }
}

extern "C" void kernel_launch(void* const* d_in, const int* in_sizes, int n_in,
                              void* d_out, int out_size, void* d_ws, size_t ws_size,
                              hipStream_t stream) {
    const float* X    = (const float*)d_in[0];
    const float* H    = (const float*)d_in[1];
    const float* edge_features = (const float*)d_in[2];
    const float* Wv   = (const float*)d_in[3];
    const float* bv   = (const float*)d_in[4];
    const float* We   = (const float*)d_in[5];
    const float* be   = (const float*)d_in[6];
    const float* vW1  = (const float*)d_in[7];
    const float* vb1  = (const float*)d_in[8];
    const float* vW2  = (const float*)d_in[9];
    const float* vb2  = (const float*)d_in[10];
    const float* eW1  = (const float*)d_in[11];
    const float* eb1  = (const float*)d_in[12];
    const float* eW2  = (const float*)d_in[13];
    const float* eb2  = (const float*)d_in[14];
    const float* Wc   = (const float*)d_in[15];
    const float* bc   = (const float*)d_in[16];
    const float* ln_e_g = (const float*)d_in[17];
    const float* ln_e_b = (const float*)d_in[18];
    const float* ln_v_g = (const float*)d_in[19];
    const float* ln_v_b = (const float*)d_in[20];
    const float* bn_g = (const float*)d_in[21];
    const float* bn_b = (const float*)d_in[22];
    const float* Wg   = (const float*)d_in[23];
    const float* bg   = (const float*)d_in[24];

    float* out_v  = (float*)d_out;            // V*COUT
    float* out_e  = out_v + NV * COUT;        // E*COUT
    float* out_att = out_e + NE * COUT;       // E

    char* w = (char*)d_ws;
    float* Xt     = (float*)w; w += (size_t)NV * COUT * 4;
    float* attn4  = (float*)w; w += (size_t)NV * NH * 4;
    float* e_ln   = (float*)w; w += (size_t)NE * COUT * 4;
    float* ecat_g = (float*)w; w += (size_t)NE * NH * COUT * 4;
    float* efp    = (float*)w; w += (size_t)4 * NE * COUT * 4;
    float* tep    = (float*)w; w += (size_t)4 * NE * COUT * 4;
    float* bn_sum = (float*)w; w += COUT * 4;
    float* bn_sq  = (float*)w; w += COUT * 4;
    int*   vdeg   = (int*)w;   w += (size_t)NV * 4;
    int*   vlist  = (int*)w;   w += (size_t)NV * VCAP * 4;
    unsigned long long* Hbits  = (unsigned long long*)w; w += (size_t)NV * NWORDS * 8;
    unsigned long long* HbitsT = (unsigned long long*)w; w += (size_t)NE * TWORDS * 8;

    hipMemsetAsync(bn_sum, 0, 2 * COUT * sizeof(float), stream);

    k_front<<<NV / 16 + NV / 4, 256, 0, stream>>>(X, Wv, bv, vW1, vb1, vW2, vb2, H,
                                                  Xt, attn4, Hbits, vdeg, vlist);
    k_transpose<<<NV / 64, 256, 0, stream>>>(Hbits, HbitsT);
    k_agg<<<NE, 256, 0, stream>>>(Xt, attn4, HbitsT, ecat_g, out_att);
    k_cpart<<<(NE / ETILE) * 4, 256, 0, stream>>>(ecat_g, edge_features, Wc, We, efp, tep);
    k_cred<<<NE / ETILE, 512, 0, stream>>>(efp, tep, bc, be, eW1, eb1, eW2, eb2,
                                           ln_e_g, ln_e_b, e_ln, bn_sum, bn_sq);
    k_bnapply<<<(NE * COUT) / 256, 256, 0, stream>>>(e_ln, bn_sum, bn_sq, bn_g, bn_b, out_e);
    k_vertex2<<<NV / 8, 512, 0, stream>>>(X, vdeg, vlist, e_ln, bn_sum, bn_sq, bn_g, bn_b,
                                          Xt, Wg, bg, ln_v_g, ln_v_b, out_v);
}